// Round 3
// baseline (25879.538 us; speedup 1.0000x reference)
//
#include <hip/hip_runtime.h>
#include <hip/hip_bf16.h>

// LSTM N=64, T=1024, D=H=512. out (N,T,H) fp32.
//
// R3 = R2 resubmit (R2 bench was a container-infra failure, no kernel signal).
// Design: 16 wgs x 1024 thr. 4 rowgroups (16 batch rows each), each handled
// by 4 wgs (sync domain = 4, was 32 in R1). Per wg: 128 h-cols = 512 a-cols;
// 16 waves x 32 a-cols (2 MFMA tiles), fp16 B-frags persistent in 256
// unified VGPRs/lane (compiler places them in AGPRs; MFMA reads A/B from
// AGPR on gfx950). Handshake: per-wg flag words on separate cache lines
// (release store / relaxed poll), no atomic RMW contention.
// x prefetched to registers one step ahead; h via 2-slot fp16 ring in ws.

#define TT 1024
#define NB 64
#define HH 512
#define LROW 1032  // 1024 K elems + 8 pad

typedef _Float16 half8 __attribute__((ext_vector_type(8)));
typedef _Float16 half4 __attribute__((ext_vector_type(4)));
typedef float floatx4 __attribute__((ext_vector_type(4)));

__global__ void init_ws_kernel(int* flags) {
    flags[threadIdx.x] = 0;   // 512 ints = 4 rg x 4 wg x 32-int stride
}

__global__ __launch_bounds__(1024, 1) void lstm_persist(
    const float* __restrict__ x, const float* __restrict__ h0,
    const float* __restrict__ Wx, const float* __restrict__ Wh,
    const float* __restrict__ b, float* __restrict__ out,
    _Float16* __restrict__ hbuf, int* __restrict__ flags)
{
    const int tid  = threadIdx.x;
    const int lane = tid & 63;
    const int wave = tid >> 6;            // 0..15
    const int rg   = blockIdx.x & 3;      // rowgroup
    const int wgc  = blockIdx.x >> 2;     // column quarter: h-cols wgc*128..+127
    const int row0 = rg << 4;

    const int gate = wave >> 2;           // 0..3 (i,f,o,g)
    const int cb   = wave & 3;            // 32-col block within the 128
    const int acol = (gate << 9) + (wgc << 7) + (cb << 5);

    __shared__ _Float16 xh[16 * LROW];       // A tile: 16 rows x [512 x | 512 h]
    __shared__ float gatebuf[4][16][132];    // gate exchange, padded

    // ---- prefetch x(t=0) into registers (overlaps weight load) ----
    const int r0 = tid >> 7;                 // rows 0..7
    const int c40 = tid & 127;               // float4 index in 512-elem row
    const int r1 = r0 + 8;                   // rows 8..15
    const float* xbase0 = x + (size_t)(row0 + r0) * (TT * 512);
    const float* xbase1 = x + (size_t)(row0 + r1) * (TT * 512);
    float4 xpre0 = ((const float4*)(xbase0))[c40];
    float4 xpre1 = ((const float4*)(xbase1))[c40];

    // ---- persistent B fragments: 2 tiles x K=1024 ----
    // B[k][n]: n = lane&15, k = kt*32 + (lane>>4)*8 + j
    const int bn = lane & 15;
    const int kq = (lane >> 4) << 3;
    half8 bfrag[2][32];
#pragma unroll
    for (int tt = 0; tt < 2; ++tt) {
        const int n = acol + (tt << 4) + bn;
#pragma unroll
        for (int kt = 0; kt < 16; ++kt) {
#pragma unroll
            for (int j = 0; j < 8; ++j) {
                int k = (kt << 5) + kq + j;
                bfrag[tt][kt][j] = (_Float16)Wx[(size_t)k * 2048 + n];
            }
        }
#pragma unroll
        for (int kt = 16; kt < 32; ++kt) {
#pragma unroll
            for (int j = 0; j < 8; ++j) {
                int k = (kt << 5) + kq + j - 512;
                bfrag[tt][kt][j] = (_Float16)Wh[(size_t)k * 2048 + n];
            }
        }
    }

    // ---- epilogue mapping: thread -> (row, col) and (row, col+64) ----
    const int erow = tid >> 6;              // 0..15
    const int ecol = tid & 63;
    const int gr  = row0 + erow;            // global batch row
    const int gh0 = (wgc << 7) + ecol;      // global h col
    const int gh1 = gh0 + 64;
    const float bi0 = b[0 * 512 + gh0], bi1 = b[0 * 512 + gh1];
    const float bf0 = b[1 * 512 + gh0], bf1 = b[1 * 512 + gh1];
    const float bo0 = b[2 * 512 + gh0], bo1 = b[2 * 512 + gh1];
    const float bg0 = b[3 * 512 + gh0], bg1 = b[3 * 512 + gh1];
    float cst0 = 0.f, cst1 = 0.f;

    const int arow = bn * LROW + kq;        // A-frag base (elems)
    int* myflag = flags + (rg << 7) + (wgc << 5);

    for (int t = 0; t < TT; ++t) {
        // ---- commit prefetched x_t to LDS (fp32 -> fp16) ----
        {
            half4 hv;
            hv.x = (_Float16)xpre0.x; hv.y = (_Float16)xpre0.y;
            hv.z = (_Float16)xpre0.z; hv.w = (_Float16)xpre0.w;
            *(half4*)&xh[r0 * LROW + (c40 << 2)] = hv;
            hv.x = (_Float16)xpre1.x; hv.y = (_Float16)xpre1.y;
            hv.z = (_Float16)xpre1.z; hv.w = (_Float16)xpre1.w;
            *(half4*)&xh[r1 * LROW + (c40 << 2)] = hv;
        }

        // ---- wait for h_t from the 4 wgs of this rowgroup, stage it ----
        if (t > 0) {
            if (tid < 4) {
                const int* fp = flags + (rg << 7) + (tid << 5);
                while (__hip_atomic_load(fp, __ATOMIC_RELAXED,
                                         __HIP_MEMORY_SCOPE_AGENT) < t) { }
                __threadfence();   // acquire: L1/L2 invalidate for the CU
            }
            __syncthreads();
            const _Float16* hsrc = hbuf + (size_t)(t & 1) * (NB * HH);
            half4 hv0 = ((const half4*)(hsrc + (size_t)(row0 + r0) * HH))[c40];
            half4 hv1 = ((const half4*)(hsrc + (size_t)(row0 + r1) * HH))[c40];
            *(half4*)&xh[r0 * LROW + 512 + (c40 << 2)] = hv0;
            *(half4*)&xh[r1 * LROW + 512 + (c40 << 2)] = hv1;
        } else {
            float4 f0 = ((const float4*)(h0 + (size_t)(row0 + r0) * HH))[c40];
            float4 f1 = ((const float4*)(h0 + (size_t)(row0 + r1) * HH))[c40];
            half4 hv;
            hv.x = (_Float16)f0.x; hv.y = (_Float16)f0.y;
            hv.z = (_Float16)f0.z; hv.w = (_Float16)f0.w;
            *(half4*)&xh[r0 * LROW + 512 + (c40 << 2)] = hv;
            hv.x = (_Float16)f1.x; hv.y = (_Float16)f1.y;
            hv.z = (_Float16)f1.z; hv.w = (_Float16)f1.w;
            *(half4*)&xh[r1 * LROW + 512 + (c40 << 2)] = hv;
        }
        __syncthreads();

        // ---- issue x prefetch for t+1 (latency hides behind MFMA+epilogue) ----
        {
            int tn = (t + 1 < TT) ? t + 1 : t;
            xpre0 = ((const float4*)(xbase0 + (size_t)tn * 512))[c40];
            xpre1 = ((const float4*)(xbase1 + (size_t)tn * 512))[c40];
        }

        // ---- MFMA: 2 tiles x K=1024, 4 independent chains ----
        floatx4 acc00 = {0,0,0,0}, acc01 = {0,0,0,0};
        floatx4 acc10 = {0,0,0,0}, acc11 = {0,0,0,0};
#pragma unroll
        for (int kt = 0; kt < 32; kt += 2) {
            half8 a0 = *(const half8*)&xh[arow + (kt << 5)];
            half8 a1 = *(const half8*)&xh[arow + ((kt + 1) << 5)];
            acc00 = __builtin_amdgcn_mfma_f32_16x16x32_f16(a0, bfrag[0][kt],     acc00, 0, 0, 0);
            acc10 = __builtin_amdgcn_mfma_f32_16x16x32_f16(a0, bfrag[1][kt],     acc10, 0, 0, 0);
            acc01 = __builtin_amdgcn_mfma_f32_16x16x32_f16(a1, bfrag[0][kt + 1], acc01, 0, 0, 0);
            acc11 = __builtin_amdgcn_mfma_f32_16x16x32_f16(a1, bfrag[1][kt + 1], acc11, 0, 0, 0);
        }
        floatx4 c0 = acc00 + acc01;
        floatx4 c1 = acc10 + acc11;

        // ---- gate exchange: C/D layout col=lane&15, row=(lane>>4)*4+v ----
        {
            const int crow = (lane >> 4) << 2;
            const int ccol = (cb << 5) + bn;
#pragma unroll
            for (int v = 0; v < 4; ++v) {
                gatebuf[gate][crow + v][ccol]      = c0[v];
                gatebuf[gate][crow + v][ccol + 16] = c1[v];
            }
        }
        __syncthreads();

        // ---- LSTM cell (2 cols/thread), write out + h ring ----
        {
            float ai0 = gatebuf[0][erow][ecol]      + bi0;
            float ai1 = gatebuf[0][erow][ecol + 64] + bi1;
            float af0 = gatebuf[1][erow][ecol]      + bf0;
            float af1 = gatebuf[1][erow][ecol + 64] + bf1;
            float ao0 = gatebuf[2][erow][ecol]      + bo0;
            float ao1 = gatebuf[2][erow][ecol + 64] + bo1;
            float ag0 = gatebuf[3][erow][ecol]      + bg0;
            float ag1 = gatebuf[3][erow][ecol + 64] + bg1;
            float ig0 = 1.f / (1.f + __expf(-ai0)), ig1 = 1.f / (1.f + __expf(-ai1));
            float fg0 = 1.f / (1.f + __expf(-af0)), fg1 = 1.f / (1.f + __expf(-af1));
            float og0 = 1.f / (1.f + __expf(-ao0)), og1 = 1.f / (1.f + __expf(-ao1));
            float gg0 = 2.f / (1.f + __expf(-2.f * ag0)) - 1.f;
            float gg1 = 2.f / (1.f + __expf(-2.f * ag1)) - 1.f;
            cst0 = fg0 * cst0 + ig0 * gg0;
            cst1 = fg1 * cst1 + ig1 * gg1;
            float hv0 = og0 * (2.f / (1.f + __expf(-2.f * cst0)) - 1.f);
            float hv1 = og1 * (2.f / (1.f + __expf(-2.f * cst1)) - 1.f);
            float* orow = out + (size_t)gr * (TT * HH) + (size_t)t * HH;
            orow[gh0] = hv0;
            orow[gh1] = hv1;
            _Float16* hrow = hbuf + (size_t)((t + 1) & 1) * (NB * HH) + (size_t)gr * HH;
            hrow[gh0] = (_Float16)hv0;
            hrow[gh1] = (_Float16)hv1;
        }

        // ---- signal: drain stores (syncthreads), wb-fence, release flag ----
        __syncthreads();
        if (tid == 0) {
            __threadfence();
            __hip_atomic_store(myflag, t + 1, __ATOMIC_RELEASE,
                               __HIP_MEMORY_SCOPE_AGENT);
        }
    }
}

extern "C" void kernel_launch(void* const* d_in, const int* in_sizes, int n_in,
                              void* d_out, int out_size, void* d_ws, size_t ws_size,
                              hipStream_t stream) {
    const float* x  = (const float*)d_in[0];
    const float* h0 = (const float*)d_in[1];
    const float* Wx = (const float*)d_in[2];
    const float* Wh = (const float*)d_in[3];
    const float* b  = (const float*)d_in[4];
    float* out = (float*)d_out;

    _Float16* hbuf = (_Float16*)d_ws;                     // 2*64*512 fp16 = 128 KB
    int* flags = (int*)((char*)d_ws + 2 * NB * HH * sizeof(_Float16));

    init_ws_kernel<<<1, 512, 0, stream>>>(flags);
    lstm_persist<<<dim3(16), dim3(1024), 0, stream>>>(x, h0, Wx, Wh, b, out, hbuf, flags);
}